// Round 1
// baseline (525.770 us; speedup 1.0000x reference)
//
#include <hip/hip_runtime.h>
#include <stddef.h>

#define B_   32
#define IN_  4096
#define OUT_ 14336

__device__ __constant__ float c_nf4[16] = {
    -1.0f, -0.6961928009986877f, -0.5250730514526367f, -0.39491748809814453f,
    -0.28444138169288635f, -0.18477343022823334f, -0.09105003625154495f, 0.0f,
    0.07958029955625534f, 0.16093020141124725f, 0.24611230194568634f,
    0.33791524171829224f, 0.44070982933044434f, 0.5626170039176941f,
    0.7229568362236023f, 1.0f};

// x (32 x 4096) -> xT (4096 x 32). Coalesced writes; reads hit L1/L2 (x is 512KB).
__global__ __launch_bounds__(256) void xpose(const float* __restrict__ x,
                                             float* __restrict__ xT) {
    int gid = blockIdx.x * 256 + threadIdx.x;   // 0..131071
    xT[gid] = x[(gid & 31) * IN_ + (gid >> 5)];
}

// One block per 64 output features. 8 waves; wave w handles k in [w*512, w*512+512).
// Lane l owns o = o0 + l with 32 fp32 accumulators (one per batch row).
// LDS partial-reduce across waves at the end; bias folded in. No atomics.
__global__ __launch_bounds__(512) void nf4_gemv(
    const int* __restrict__ codes, const float* __restrict__ absmax,
    const float* __restrict__ xT, const float* __restrict__ bias,
    float* __restrict__ out) {
    __shared__ float lut[16];
    __shared__ float partial[32 * 512];   // [b][w*64+l], 64 KB

    const int tid = threadIdx.x;
    if (tid < 16) lut[tid] = c_nf4[tid];
    __syncthreads();

    const int w = tid >> 6;               // wave id 0..7
    const int l = tid & 63;               // lane
    const int o = blockIdx.x * 64 + l;    // output feature
    const int kbase = w * 512;            // this wave's k chunk

    float acc[32];
#pragma unroll
    for (int b = 0; b < 32; ++b) acc[b] = 0.f;

    // 8 absmax scales for this lane's chunk: idx = o*64 + w*8 + (0..7), contiguous.
    const float4* amp = (const float4*)(absmax + (size_t)o * 64 + w * 8);
    float4 am0 = amp[0];
    float4 am1 = amp[1];

    const int4* crow = (const int4*)(codes + (size_t)o * IN_ + kbase);

#pragma unroll
    for (int h = 0; h < 2; ++h) {
        float4 amv = (h == 0) ? am0 : am1;
#pragma unroll 1
        for (int kg2 = 0; kg2 < 4; ++kg2) {
            float amax = kg2 == 0 ? amv.x : kg2 == 1 ? amv.y : kg2 == 2 ? amv.z : amv.w;
            const int kgrp = h * 4 + kg2;                 // 0..7 (64 k each)
            const int4* cp = crow + kgrp * 16;
            const float4* xp = (const float4*)(xT + (size_t)(kbase + kgrp * 64) * 32);
#pragma unroll 2
            for (int kv4 = 0; kv4 < 4; ++kv4) {
                int4 c4[4];
#pragma unroll
                for (int u = 0; u < 4; ++u) c4[u] = cp[kv4 * 4 + u];  // 64B/lane
#pragma unroll
                for (int u = 0; u < 4; ++u) {
                    const int cs[4] = {c4[u].x, c4[u].y, c4[u].z, c4[u].w};
#pragma unroll
                    for (int j = 0; j < 4; ++j) {
                        float wv = lut[cs[j]] * amax;
                        const float4* xr = xp + (size_t)(kv4 * 16 + u * 4 + j) * 8;
#pragma unroll
                        for (int b4 = 0; b4 < 8; ++b4) {
                            float4 xv = xr[b4];           // wave-uniform addr, L1 hit
                            acc[b4 * 4 + 0] += xv.x * wv;
                            acc[b4 * 4 + 1] += xv.y * wv;
                            acc[b4 * 4 + 2] += xv.z * wv;
                            acc[b4 * 4 + 3] += xv.w * wv;
                        }
                    }
                }
            }
        }
    }

    // partial[b*512 + w*64 + l] — bank = l%32 → 2-way (free)
#pragma unroll
    for (int b = 0; b < 32; ++b) partial[b * 512 + w * 64 + l] = acc[b];
    __syncthreads();

    // 2048 outputs per block, 4 per thread; coalesced writes; bias folded in.
#pragma unroll
    for (int pass = 0; pass < 4; ++pass) {
        int idx = pass * 512 + tid;
        int ol = idx & 63;
        int b = idx >> 6;
        float s = 0.f;
#pragma unroll
        for (int ww = 0; ww < 8; ++ww) s += partial[b * 512 + ww * 64 + ol];
        int oo = blockIdx.x * 64 + ol;
        out[(size_t)b * OUT_ + oo] = s + bias[oo];
    }
}

extern "C" void kernel_launch(void* const* d_in, const int* in_sizes, int n_in,
                              void* d_out, int out_size, void* d_ws, size_t ws_size,
                              hipStream_t stream) {
    const float* x      = (const float*)d_in[0];
    const int*   codes  = (const int*)d_in[1];
    const float* absmax = (const float*)d_in[2];
    const float* bias   = (const float*)d_in[3];
    float* out = (float*)d_out;
    float* xT  = (float*)d_ws;   // 4096*32*4 = 512 KB scratch

    xpose<<<dim3(IN_ * B_ / 256), 256, 0, stream>>>(x, xT);
    nf4_gemv<<<dim3(OUT_ / 64), 512, 0, stream>>>(codes, absmax, xT, bias, out);
}

// Round 3
// 323.881 us; speedup vs baseline: 1.6233x; 1.6233x over previous
//
#include <hip/hip_runtime.h>
#include <stddef.h>
#include <stdint.h>

#define B_   32
#define IN_  4096
#define OUT_ 14336

typedef short v8s __attribute__((ext_vector_type(8)));
typedef float v4f __attribute__((ext_vector_type(4)));

__device__ __constant__ float c_nf4[16] = {
    -1.0f, -0.6961928009986877f, -0.5250730514526367f, -0.39491748809814453f,
    -0.28444138169288635f, -0.18477343022823334f, -0.09105003625154495f, 0.0f,
    0.07958029955625534f, 0.16093020141124725f, 0.24611230194568634f,
    0.33791524171829224f, 0.44070982933044434f, 0.5626170039176941f,
    0.7229568362236023f, 1.0f};

__device__ __forceinline__ unsigned f2bf_u(float f) {
    union { float f; unsigned u; } v; v.f = f;
    return (v.u + 0x7FFFu + ((v.u >> 16) & 1u)) >> 16;   // RNE, no NaN inputs
}
__device__ __forceinline__ unsigned pack2(float lo, float hi) {
    return f2bf_u(lo) | (f2bf_u(hi) << 16);
}

// x[32][4096] f32 -> xB bf16 in B-fragment layout for mfma_f32_16x16x32_bf16.
// Fragment t = (kt*2 + bt)*64 + l holds B[k = kt*32 + (l>>4)*8 + j][n = bt*16 + (l&15)]
// at xB uint4-index t (8 bf16 per lane, j = vector element).
__global__ __launch_bounds__(256) void prep(const float* __restrict__ x,
                                            unsigned* __restrict__ xB) {
    int t  = blockIdx.x * 256 + threadIdx.x;   // 0..16383
    int kt = t >> 7;
    int bt = (t >> 6) & 1;
    int l  = t & 63;
    int b  = bt * 16 + (l & 15);
    int k0 = kt * 32 + (l >> 4) * 8;
    const float* xr = x + (size_t)b * IN_ + k0;
    float4 a = *(const float4*)xr;
    float4 c = *(const float4*)(xr + 4);
    uint4 w;
    w.x = pack2(a.x, a.y);
    w.y = pack2(a.z, a.w);
    w.z = pack2(c.x, c.y);
    w.w = pack2(c.z, c.w);
    *(uint4*)(xB + (size_t)t * 4) = w;
}

// Grid 224 x 256. Wave w: o-tile [blk*64 + w*16, +16), full K=4096.
// Per k-step (32 k): A-frag = dequantized codes (lane: row m=l&15, k=q*8+j),
// B-frags from xB (coalesced dwordx4), 2 MFMAs (b-tiles 0,1).
// No LDS writes, no barriers, no manual waitcnt in the K-loop.
__global__ __launch_bounds__(256) void nf4_mfma(
    const int* __restrict__ codes, const float* __restrict__ absmax,
    const unsigned* __restrict__ xB, const float* __restrict__ bias,
    float* __restrict__ out) {
    __shared__ float lut[16];
    if (threadIdx.x < 16) lut[threadIdx.x] = c_nf4[threadIdx.x];
    __syncthreads();

    const int w  = threadIdx.x >> 6;
    const int l  = threadIdx.x & 63;
    const int o0 = blockIdx.x * 64 + w * 16;
    const int m  = l & 15;
    const int q  = l >> 4;

    const int*   crow  = codes + (size_t)(o0 + m) * IN_ + q * 8;
    const float* amrow = absmax + (size_t)(o0 + m) * 64;
    const uint4* xbp   = (const uint4*)xB + l;   // + (kt*2+bt)*64

    v4f acc0 = {0.f, 0.f, 0.f, 0.f};
    v4f acc1 = {0.f, 0.f, 0.f, 0.f};

#pragma unroll 4
    for (int kt = 0; kt < 128; ++kt) {
        int4 c0 = *(const int4*)(crow + (size_t)kt * 32);
        int4 c1 = *(const int4*)(crow + (size_t)kt * 32 + 4);
        uint4 b0 = xbp[(size_t)kt * 128];        // b-tile 0
        uint4 b1 = xbp[(size_t)kt * 128 + 64];   // b-tile 1
        float am = amrow[kt >> 1];               // 64-k absmax block

        union { uint4 u; v8s v; } a, f0, f1;
        a.u.x = pack2(lut[c0.x] * am, lut[c0.y] * am);
        a.u.y = pack2(lut[c0.z] * am, lut[c0.w] * am);
        a.u.z = pack2(lut[c1.x] * am, lut[c1.y] * am);
        a.u.w = pack2(lut[c1.z] * am, lut[c1.w] * am);
        f0.u = b0;
        f1.u = b1;
        acc0 = __builtin_amdgcn_mfma_f32_16x16x32_bf16(a.v, f0.v, acc0, 0, 0, 0);
        acc1 = __builtin_amdgcn_mfma_f32_16x16x32_bf16(a.v, f1.v, acc1, 0, 0, 0);
    }

    // D layout: col = l&15 (= b within tile), row = q*4 + r (= o offset)
    const int bc = l & 15;
    const int ob = o0 + q * 4;
#pragma unroll
    for (int r = 0; r < 4; ++r) {
        float bv = bias[ob + r];
        out[(size_t)bc * OUT_ + ob + r]        = acc0[r] + bv;
        out[(size_t)(bc + 16) * OUT_ + ob + r] = acc1[r] + bv;
    }
}

extern "C" void kernel_launch(void* const* d_in, const int* in_sizes, int n_in,
                              void* d_out, int out_size, void* d_ws, size_t ws_size,
                              hipStream_t stream) {
    const float* x      = (const float*)d_in[0];
    const int*   codes  = (const int*)d_in[1];
    const float* absmax = (const float*)d_in[2];
    const float* bias   = (const float*)d_in[3];
    float* out = (float*)d_out;
    unsigned* xB = (unsigned*)d_ws;   // 256 KB (ws known >= 512 KB from round 1)

    prep<<<dim3(64), 256, 0, stream>>>(x, xB);
    nf4_mfma<<<dim3(OUT_ / 64), 256, 0, stream>>>(codes, absmax, xB, bias, out);
}